// Round 14
// baseline (983.968 us; speedup 1.0000x reference)
//
#include <hip/hip_runtime.h>
#include <math.h>

// Problem constants: B=2, S=256, IN=80, H=128, NC=40, WSEG=64, F2=256
// Output layout (floats): cls_out[2*256*40]=20480 @0, bin_out[2*256*2]=1024 @20480,
//                         bmask[2*256]=512 @21504, pred_scores[2] @22016

#define OFF_BIN 20480
#define OFF_BM  21504
#define OFF_PRED 22016

__device__ __forceinline__ float preluf(float x, float a) { return x >= 0.f ? x : a * x; }
__device__ __forceinline__ float sigf(float x) { return 1.f / (1.f + __expf(-x)); }
// exact identity tanh(x) = 1 - 2/(e^{2x}+1); hardware v_exp_f32, no branches
__device__ __forceinline__ float tanh_fast(float x) { return 1.f - 2.f / (__expf(2.f * x) + 1.f); }

// ---------------- input projection as tiled GEMM (coalesced):
__global__ __launch_bounds__(256) void k_gemm(const float* __restrict__ A,
                                              const float* __restrict__ B,
                                              int Adim, int K,
                                              const float* __restrict__ wf,
                                              const float* __restrict__ bf,
                                              const float* __restrict__ wb,
                                              const float* __restrict__ bbv,
                                              float* __restrict__ outF,
                                              float* __restrict__ outB) {
    int mtile = blockIdx.y;
    int dir = mtile >> 3;
    const float* W = dir ? wb : wf;
    const float* bias = dir ? bbv : bf;
    float* out = dir ? outB : outF;
    int g0 = (mtile & 7) << 6;
    int tb0 = blockIdx.x << 6;
    int tid = threadIdx.x;
    int Bdim = K - Adim;

    __shared__ float Ws[16][68];
    __shared__ float Xs[16][68];

    int r = tid >> 2, c4 = tid & 3;
    int tbr = tb0 + r;
    int hr = ((tbr & 1) << 8) | (tbr >> 1);
    int ty = tid >> 4;
    int tx = tid & 15;
    float acc[4][4] = {};

    for (int k0 = 0; k0 < K; k0 += 16) {
        float4 wv = *(const float4*)(W + (size_t)(g0 + r) * K + k0 + (c4 << 2));
        const float* src = (k0 < Adim) ? (A + (size_t)hr * Adim + k0)
                                       : (B + (size_t)hr * Bdim + (k0 - Adim));
        float4 xv = *(const float4*)(src + (c4 << 2));
        __syncthreads();
        int kc = c4 << 2;
        Ws[kc + 0][r] = wv.x; Ws[kc + 1][r] = wv.y; Ws[kc + 2][r] = wv.z; Ws[kc + 3][r] = wv.w;
        Xs[kc + 0][r] = xv.x; Xs[kc + 1][r] = xv.y; Xs[kc + 2][r] = xv.z; Xs[kc + 3][r] = xv.w;
        __syncthreads();
#pragma unroll
        for (int kk = 0; kk < 16; ++kk) {
            float4 wq = *(const float4*)&Ws[kk][ty << 2];
            float4 xq = *(const float4*)&Xs[kk][tx << 2];
            acc[0][0] += wq.x * xq.x; acc[0][1] += wq.x * xq.y; acc[0][2] += wq.x * xq.z; acc[0][3] += wq.x * xq.w;
            acc[1][0] += wq.y * xq.x; acc[1][1] += wq.y * xq.y; acc[1][2] += wq.y * xq.z; acc[1][3] += wq.y * xq.w;
            acc[2][0] += wq.z * xq.x; acc[2][1] += wq.z * xq.y; acc[2][2] += wq.z * xq.z; acc[2][3] += wq.z * xq.w;
            acc[3][0] += wq.w * xq.x; acc[3][1] += wq.w * xq.y; acc[3][2] += wq.w * xq.z; acc[3][3] += wq.w * xq.w;
        }
    }
    int gq = g0 + (ty << 2);
    float b0 = bias[gq], b1 = bias[gq + 1], b2 = bias[gq + 2], b3 = bias[gq + 3];
#pragma unroll
    for (int j = 0; j < 4; ++j) {
        int tb = tb0 + (tx << 2) + j;
        float4 v = make_float4(acc[0][j] + b0, acc[1][j] + b1, acc[2][j] + b2, acc[3][j] + b3);
        *(float4*)(out + (size_t)tb * 512 + gq) = v;
    }
}

// ---------------- LSTM scan v5: R8 structure + 8-step-batched global I/O.
// Per-step __syncthreads drains vmcnt(0); with per-step pre-loads/h-stores that
// exposed ~300-600 cyc of global latency EVERY step. Now pre is prefetched for
// 8 steps into registers and h is buffered 8 steps then flushed -> one drain
// region per 8 steps. GEMV accumulators split 2-way (dep chain 128->64 cyc).
__global__ __launch_bounds__(512, 2) void k_lstm(const float* __restrict__ pre_f,
                                                 const float* __restrict__ pre_b,
                                                 const float* __restrict__ whh_f,
                                                 const float* __restrict__ whh_b,
                                                 float* __restrict__ hout_f,
                                                 float* __restrict__ hout_b) {
    const int dir = blockIdx.x >> 1;
    const int b = blockIdx.x & 1;
    const float* pre = dir ? pre_b : pre_f;
    const float* whh = dir ? whh_b : whh_f;
    float* hout = dir ? hout_b : hout_f;
    const int tid = threadIdx.x;
    const int c = tid >> 7;        // k-chunk 0..3 (wave-uniform)
    const int gg = tid & 127;      // hidden unit 0..127
    const int k0 = c << 5;

    float w[4][32];
#pragma unroll
    for (int j = 0; j < 4; ++j) {
#pragma unroll
        for (int k = 0; k < 32; k += 4) {
            float4 v = *(const float4*)(whh + (size_t)((j << 7) + gg) * 128 + k0 + k);
            w[j][k] = v.x; w[j][k + 1] = v.y; w[j][k + 2] = v.z; w[j][k + 3] = v.w;
        }
    }

    __shared__ __align__(16) float hl[128];
    __shared__ float4 part[4][128];
    if (tid < 128) hl[tid] = 0.f;
    float cst = 0.f;
    float pf0[8], pf1[8], pf2[8], pf3[8], hb8[8];
    __syncthreads();

    for (int blk = 0; blk < 32; ++blk) {
        if (tid < 128) {
#pragma unroll
            for (int s = 0; s < 8; ++s) {
                int step = (blk << 3) + s;
                int t = dir ? (255 - step) : step;
                const float* pp = pre + ((size_t)t * 2 + b) * 512;
                pf0[s] = pp[gg]; pf1[s] = pp[128 + gg];
                pf2[s] = pp[256 + gg]; pf3[s] = pp[384 + gg];
            }
        }
#pragma unroll
        for (int s = 0; s < 8; ++s) {
            float a0 = 0.f, a1 = 0.f, a2 = 0.f, a3 = 0.f;
            float e0 = 0.f, e1 = 0.f, e2 = 0.f, e3 = 0.f;
#pragma unroll
            for (int k = 0; k < 32; k += 8) {
                float4 hA = *(const float4*)(hl + k0 + k);       // wave-uniform broadcast
                float4 hB = *(const float4*)(hl + k0 + k + 4);
                a0 += w[0][k] * hA.x + w[0][k + 1] * hA.y + w[0][k + 2] * hA.z + w[0][k + 3] * hA.w;
                e0 += w[0][k + 4] * hB.x + w[0][k + 5] * hB.y + w[0][k + 6] * hB.z + w[0][k + 7] * hB.w;
                a1 += w[1][k] * hA.x + w[1][k + 1] * hA.y + w[1][k + 2] * hA.z + w[1][k + 3] * hA.w;
                e1 += w[1][k + 4] * hB.x + w[1][k + 5] * hB.y + w[1][k + 6] * hB.z + w[1][k + 7] * hB.w;
                a2 += w[2][k] * hA.x + w[2][k + 1] * hA.y + w[2][k + 2] * hA.z + w[2][k + 3] * hA.w;
                e2 += w[2][k + 4] * hB.x + w[2][k + 5] * hB.y + w[2][k + 6] * hB.z + w[2][k + 7] * hB.w;
                a3 += w[3][k] * hA.x + w[3][k + 1] * hA.y + w[3][k + 2] * hA.z + w[3][k + 3] * hA.w;
                e3 += w[3][k + 4] * hB.x + w[3][k + 5] * hB.y + w[3][k + 6] * hB.z + w[3][k + 7] * hB.w;
            }
            part[c][gg] = make_float4(a0 + e0, a1 + e1, a2 + e2, a3 + e3);
            __syncthreads();
            if (tid < 128) {
                float4 q0 = part[0][gg], q1 = part[1][gg], q2 = part[2][gg], q3 = part[3][gg];
                float gi = pf0[s] + ((q0.x + q1.x) + (q2.x + q3.x));
                float gf = pf1[s] + ((q0.y + q1.y) + (q2.y + q3.y));
                float gG = pf2[s] + ((q0.z + q1.z) + (q2.z + q3.z));
                float go = pf3[s] + ((q0.w + q1.w) + (q2.w + q3.w));
                cst = sigf(gf) * cst + sigf(gi) * tanh_fast(gG);
                float h = sigf(go) * tanh_fast(cst);
                hl[gg] = h;
                hb8[s] = h;
            }
            __syncthreads();
        }
        if (tid < 128) {
            int base = blk << 3;
#pragma unroll
            for (int s = 0; s < 8; ++s) {
                int t = dir ? (255 - (base + s)) : (base + s);
                hout[(size_t)(((b << 8) + t) << 7) + gg] = hb8[s];
            }
        }
    }
}

// ---------------- fused features (unchanged)
__global__ __launch_bounds__(256) void k_feats(const float* __restrict__ h1f,
                                               const float* __restrict__ h1b,
                                               const float* __restrict__ ws1,
                                               const float* __restrict__ bs1,
                                               const float* a_s0,
                                               float* __restrict__ Pd,
                                               float* __restrict__ Pe,
                                               const float* ac0p, const float* __restrict__ wc1,
                                               const float* __restrict__ bc1, const float* ac1p,
                                               const float* __restrict__ wc2, const float* __restrict__ bc2,
                                               const float* ab0p, const float* __restrict__ wb1,
                                               const float* __restrict__ bb1, const float* ab1p,
                                               const float* __restrict__ wb2, const float* __restrict__ bb2,
                                               float* __restrict__ out,
                                               float* __restrict__ cum) {
    __shared__ __align__(16) float xa[256];
    __shared__ __align__(16) float xb2[256];
    __shared__ __align__(16) float hc[80];
    __shared__ __align__(16) float hb[80];
    int bid = blockIdx.x;
    int tid = threadIdx.x;
    int kk = tid & 127;
    if (bid < 512) {
        int row = bid;
        float a0 = a_s0[0];
        float v = ((tid < 128) ? h1f : h1b)[(size_t)row * 128 + kk];
        xa[tid] = preluf(v, a0);
        __syncthreads();
        const float4* p4 = (const float4*)xa;
        if (tid < 100) {
            const float4* wr = (const float4*)(ws1 + (size_t)tid * 768 + 256);
            float acc = bs1[tid];
#pragma unroll 8
            for (int q = 0; q < 64; ++q) {
                float4 w4 = wr[q], x4 = p4[q];
                acc += w4.x * x4.x + w4.y * x4.y + w4.z * x4.z + w4.w * x4.w;
            }
            Pd[(size_t)row * 100 + tid] = acc;
        } else if (tid >= 128 && tid < 228) {
            int u = tid - 128;
            const float4* wr = (const float4*)(ws1 + (size_t)u * 768 + 512);
            float acc = 0.f;
#pragma unroll 8
            for (int q = 0; q < 64; ++q) {
                float4 w4 = wr[q], x4 = p4[q];
                acc += w4.x * x4.x + w4.y * x4.y + w4.z * x4.z + w4.w * x4.w;
            }
            Pe[(size_t)row * 100 + u] = acc;
        }
    } else if (bid < 1024) {
        int row = bid - 512;
        float ac0 = ac0p[0], ac1 = ac1p[0], ab0 = ab0p[0], ab1 = ab1p[0];
        float v = ((tid < 128) ? h1f : h1b)[(size_t)row * 128 + kk];
        xa[tid] = preluf(v, ac0);
        xb2[tid] = preluf(v, ab0);
        __syncthreads();
        if (tid < 80) {
            const float4* wr = (const float4*)(wc1 + (size_t)tid * 256);
            const float4* x4 = (const float4*)xa;
            float acc = bc1[tid];
#pragma unroll 8
            for (int q = 0; q < 64; ++q) {
                float4 w4 = wr[q], p = x4[q];
                acc += w4.x * p.x + w4.y * p.y + w4.z * p.z + w4.w * p.w;
            }
            hc[tid] = preluf(acc, ac1);
        } else if (tid >= 128 && tid < 208) {
            int u = tid - 128;
            const float4* wr = (const float4*)(wb1 + (size_t)u * 256);
            const float4* x4 = (const float4*)xb2;
            float acc = bb1[u];
#pragma unroll 8
            for (int q = 0; q < 64; ++q) {
                float4 w4 = wr[q], p = x4[q];
                acc += w4.x * p.x + w4.y * p.y + w4.z * p.z + w4.w * p.w;
            }
            hb[u] = preluf(acc, ab1);
        }
        __syncthreads();
        if (tid < 40) {
            const float4* wr = (const float4*)(wc2 + (size_t)tid * 80);
            const float4* h4 = (const float4*)hc;
            float acc = bc2[tid];
#pragma unroll
            for (int q = 0; q < 20; ++q) {
                float4 w4 = wr[q], p = h4[q];
                acc += w4.x * p.x + w4.y * p.y + w4.z * p.z + w4.w * p.w;
            }
            out[(size_t)row * 40 + tid] = acc;
        } else if (tid >= 64 && tid < 66) {
            int j = tid - 64;
            const float4* wr = (const float4*)(wb2 + (size_t)j * 80);
            const float4* h4 = (const float4*)hb;
            float acc = bb2[j];
#pragma unroll
            for (int q = 0; q < 20; ++q) {
                float4 w4 = wr[q], p = h4[q];
                acc += w4.x * p.x + w4.y * p.y + w4.z * p.z + w4.w * p.w;
            }
            out[OFF_BIN + (size_t)row * 2 + j] = acc;
        }
    } else {
        int b = bid - 1024;
        const float* src = (tid < 128) ? h1f : h1b;
        float run = 0.f;
#pragma unroll 8
        for (int t = 0; t < 256; ++t) {
            float v = src[(size_t)(((b << 8) + t) << 7) + kk];
            cum[(size_t)(((b << 8) + t) << 8) + tid] = run + v;
            run += v;
        }
    }
}

// ---------------- pairwise scores v5: d-tile 64 x e-tile 4 (256 pairs/block ->
// unique W s_loads per pair halved; wave-pairs (w, w+4) share identical W streams
// for K$ hits). k processed in two 128-halves so cumd LDS stays 33 KB. 512 blocks
// x 512 thr. lane = dd (0..63); wave w: ug = w&3, eh = w>>2; acc = 25u x 2e.
__global__ __launch_bounds__(512, 2) void k_scores(const float* __restrict__ cum,
                                                   const float* __restrict__ ws1,
                                                   const float* __restrict__ ws2,
                                                   const float* __restrict__ bs2,
                                                   const float* __restrict__ Pd,
                                                   const float* __restrict__ Pe,
                                                   const float* a_s0p, const float* a_s1p,
                                                   float* __restrict__ scT) {
    int bid = blockIdx.x;
    int dt = bid & 3, et = (bid >> 2) & 63, b = bid >> 8;
    int d0 = dt << 6, e0 = et << 2;
    int tid = threadIdx.x;
    __shared__ float cumdh[64][129];   // stride 129 -> 2-way bank aliasing (free)
    __shared__ float cumeh[4][129];
    __shared__ float red[4][4][64];
    float a0 = a_s0p[0], a1 = a_s1p[0];

    int wv = tid >> 6;
    int ug = __builtin_amdgcn_readfirstlane(wv & 3);
    int eh = __builtin_amdgcn_readfirstlane(wv >> 2);
    int dd = tid & 63;
    int ea = eh << 1, ebn = ea + 1;
    float acc0[25], acc1[25];
#pragma unroll
    for (int t = 0; t < 25; ++t) { acc0[t] = 0.f; acc1[t] = 0.f; }
    const float* wc = ws1 + (size_t)(ug * 25) * 768;  // c-block columns are [0,256)

    for (int half = 0; half < 2; ++half) {
        int hk = half << 7;
        __syncthreads();   // previous half's reads done before restage
        // stage cumd half: row = tid&63, 16-float chunk = wave
        {
            int r = tid & 63, wq = tid >> 6;
            const float4* src = (const float4*)(cum + (size_t)(((b << 8) + (d0 + r)) << 8) + hk + (wq << 4));
            float* dst = &cumdh[r][wq << 4];
#pragma unroll
            for (int x = 0; x < 4; ++x) {
                float4 v = src[x];
                dst[(x << 2) + 0] = v.x; dst[(x << 2) + 1] = v.y;
                dst[(x << 2) + 2] = v.z; dst[(x << 2) + 3] = v.w;
            }
        }
        // stage cume half: 4 rows x 128
        if (tid < 128) {
            int er = tid >> 5, j = tid & 31;
            float4 v = *((const float4*)(cum + (size_t)(((b << 8) + (e0 + er)) << 8) + hk) + j);
            float* dst = &cumeh[er][j << 2];
            dst[0] = v.x; dst[1] = v.y; dst[2] = v.z; dst[3] = v.w;
        }
        __syncthreads();

        for (int k = 0; k < 128; k += 4) {
            float cd0 = cumdh[dd][k], cd1 = cumdh[dd][k + 1],
                  cd2 = cumdh[dd][k + 2], cd3 = cumdh[dd][k + 3];
            float4 ya = make_float4(preluf(cumeh[ea][k] - cd0, a0), preluf(cumeh[ea][k + 1] - cd1, a0),
                                    preluf(cumeh[ea][k + 2] - cd2, a0), preluf(cumeh[ea][k + 3] - cd3, a0));
            float4 yb = make_float4(preluf(cumeh[ebn][k] - cd0, a0), preluf(cumeh[ebn][k + 1] - cd1, a0),
                                    preluf(cumeh[ebn][k + 2] - cd2, a0), preluf(cumeh[ebn][k + 3] - cd3, a0));
#pragma unroll
            for (int t = 0; t < 25; ++t) {
                float4 wq = *(const float4*)(wc + (size_t)t * 768 + hk + k);  // uniform -> s_load
                acc0[t] += ya.x * wq.x + ya.y * wq.y + ya.z * wq.z + ya.w * wq.w;
                acc1[t] += yb.x * wq.x + yb.y * wq.y + yb.z * wq.z + yb.w * wq.w;
            }
        }
    }

    const float* pdrow = Pd + (size_t)((b << 8) + d0 + dd) * 100;
    {
        const float* perow = Pe + (size_t)((b << 8) + e0 + ea) * 100;
        float part = 0.f;
#pragma unroll
        for (int t = 0; t < 25; ++t) {
            int u = ug * 25 + t;
            float h = acc0[t] + pdrow[u] + perow[u];
            part += preluf(h, a1) * ws2[u];
        }
        red[ug][ea][dd] = part;
    }
    {
        const float* perow = Pe + (size_t)((b << 8) + e0 + ebn) * 100;
        float part = 0.f;
#pragma unroll
        for (int t = 0; t < 25; ++t) {
            int u = ug * 25 + t;
            float h = acc1[t] + pdrow[u] + perow[u];
            part += preluf(h, a1) * ws2[u];
        }
        red[ug][ebn][dd] = part;
    }
    __syncthreads();
    if (tid < 256) {
        int e = tid >> 6, l2 = tid & 63;
        float s = red[0][e][l2] + red[1][e][l2] + red[2][e][l2] + red[3][e][l2] + bs2[0];
        scT[(size_t)(((b << 8) + (e0 + e)) << 8) + d0 + l2] = s;
    }
}

// ---------------- banded DP + backtrack (R11 version, unchanged)
__device__ __forceinline__ void argmax_dpp(float& v, int& ki) {
#define AD_STEP(CTRL, RMASK)                                                                    \
    {                                                                                           \
        int mv = __builtin_amdgcn_update_dpp(__float_as_int(v), __float_as_int(v), CTRL, RMASK, 0xf, false); \
        int mk = __builtin_amdgcn_update_dpp(ki, ki, CTRL, RMASK, 0xf, false);                  \
        float fv = __int_as_float(mv);                                                          \
        bool take = (fv > v) || (fv == v && mk < ki);                                           \
        v = take ? fv : v;                                                                      \
        ki = take ? mk : ki;                                                                    \
    }
    AD_STEP(0x111, 0xf)   // row_shr:1
    AD_STEP(0x112, 0xf)   // row_shr:2
    AD_STEP(0x114, 0xf)   // row_shr:4
    AD_STEP(0x118, 0xf)   // row_shr:8
    AD_STEP(0x142, 0xa)   // row_bcast15
    AD_STEP(0x143, 0xc)   // row_bcast31 -> lane 63 = global
#undef AD_STEP
}

__global__ __launch_bounds__(128) void k_dp(const float* __restrict__ scT,
                                            const int* __restrict__ lengths,
                                            float* __restrict__ out) {
    __shared__ int bp[2][256];
    __shared__ float bm[2][256];
    int tid = threadIdx.x;
    for (int i = tid; i < 512; i += 128) {
        ((int*)bp)[i] = 0;
        ((float*)bm)[i] = 0.f;
    }
    __syncthreads();
    int b = tid >> 6, ln = tid & 63;
    const float* sb = scT + ((size_t)b << 16);
    int lenm1 = lengths[b] - 1;
    float wreg = 0.f;
    float bestFinal = 0.f;
    int jcur = (ln < 1) ? ln : ln - 64;
    float sc_next = sb[(1 << 8) + ((jcur < 0) ? 0 : jcur)];
    for (int i = 1; i < 256; ++i) {
        float sc = sc_next;
        int j = jcur;
        if (i < 255) {
            int m2 = (i + 1) & 63;
            int base2 = (i + 1) - m2;
            int j2 = (ln < m2) ? (base2 + ln) : (base2 + ln - 64);
            jcur = j2;
            sc_next = sb[((i + 1) << 8) + ((j2 < 0) ? 0 : j2)];
        }
        float v = (j >= 0) ? (wreg + sc) : -1000000000.0f;
        int ki = j;
        argmax_dpp(v, ki);
        float bv = __uint_as_float(__builtin_amdgcn_readlane(__float_as_uint(v), 63));
        int bk = __builtin_amdgcn_readlane(ki, 63);
        if (ln == (i & 63)) wreg = bv;
        if (ln == 0) bp[b][i] = bk;
        if (i == lenm1) bestFinal = bv;
    }
    if (ln == 0) out[OFF_PRED + b] = bestFinal;
    __syncthreads();
    if (tid < 2) {
        int bb = tid;
        int cur = lengths[bb] - 1;
        for (int it = 0; it < 256; ++it) {
            bm[bb][cur] = 1.f;
            int prev = bp[bb][cur];
            cur = (cur > 0) ? prev : 0;
        }
    }
    __syncthreads();
    for (int i = tid; i < 512; i += 128) out[OFF_BM + i] = ((float*)bm)[i];
}

extern "C" void kernel_launch(void* const* d_in, const int* in_sizes, int n_in,
                              void* d_out, int out_size, void* d_ws, size_t ws_size,
                              hipStream_t stream) {
    const float* x     = (const float*)d_in[0];
    const int* lengths = (const int*)d_in[1];
    const float* wih0f = (const float*)d_in[2];
    const float* whh0f = (const float*)d_in[3];
    const float* b0f   = (const float*)d_in[4];
    const float* wih0b = (const float*)d_in[5];
    const float* whh0b = (const float*)d_in[6];
    const float* b0b   = (const float*)d_in[7];
    const float* wih1f = (const float*)d_in[8];
    const float* whh1f = (const float*)d_in[9];
    const float* b1f   = (const float*)d_in[10];
    const float* wih1b = (const float*)d_in[11];
    const float* whh1b = (const float*)d_in[12];
    const float* b1b   = (const float*)d_in[13];
    const float* a_s0  = (const float*)d_in[14];
    const float* w_s1  = (const float*)d_in[15];
    const float* b_s1  = (const float*)d_in[16];
    const float* a_s1  = (const float*)d_in[17];
    const float* w_s2  = (const float*)d_in[18];
    const float* b_s2  = (const float*)d_in[19];
    const float* a_c0  = (const float*)d_in[20];
    const float* w_c1  = (const float*)d_in[21];
    const float* b_c1  = (const float*)d_in[22];
    const float* a_c1  = (const float*)d_in[23];
    const float* w_c2  = (const float*)d_in[24];
    const float* b_c2  = (const float*)d_in[25];
    const float* a_b0  = (const float*)d_in[26];
    const float* w_b1  = (const float*)d_in[27];
    const float* b_b1  = (const float*)d_in[28];
    const float* a_b1  = (const float*)d_in[29];
    const float* w_b2  = (const float*)d_in[30];
    const float* b_b2  = (const float*)d_in[31];

    float* wsf = (float*)d_ws;
    float* preF = wsf;                 // 262144
    float* preB = wsf + 262144;        // 262144
    float* h0f  = wsf + 524288;        // 65536
    float* h0b  = wsf + 589824;        // 65536
    float* h1f  = wsf + 655360;        // 65536
    float* h1b  = wsf + 720896;        // 65536
    float* cum  = wsf + 786432;        // 131072
    float* Pd   = wsf + 917504;        // 51200
    float* Pe   = wsf + 968704;        // 51200
    float* scT  = wsf + 1019904;       // 131072
    float* out  = (float*)d_out;

    // layer 0 (tiled GEMM input projection, both dirs)
    k_gemm<<<dim3(8, 16), 256, 0, stream>>>(x, x, 80, 80, wih0f, b0f, wih0b, b0b, preF, preB);
    k_lstm<<<4, 512, 0, stream>>>(preF, preB, whh0f, whh0b, h0f, h0b);
    // layer 1
    k_gemm<<<dim3(8, 16), 256, 0, stream>>>(h0f, h0b, 128, 256, wih1f, b1f, wih1b, b1b, preF, preB);
    k_lstm<<<4, 512, 0, stream>>>(preF, preB, whh1f, whh1b, h1f, h1b);
    // fused features: Pd/Pe + heads + cumsum
    k_feats<<<1026, 256, 0, stream>>>(h1f, h1b, w_s1, b_s1, a_s0, Pd, Pe,
                                      a_c0, w_c1, b_c1, a_c1, w_c2, b_c2,
                                      a_b0, w_b1, b_b1, a_b1, w_b2, b_b2, out, cum);
    // pairwise scores (d64 x e4, k-halves, K$-shared W streams)
    k_scores<<<512, 512, 0, stream>>>(cum, w_s1, w_s2, b_s2, Pd, Pe, a_s0, a_s1, scT);
    // DP + backtrack (DPP argmax + register window)
    k_dp<<<1, 128, 0, stream>>>(scT, lengths, out);
}

// Round 15
// 886.779 us; speedup vs baseline: 1.1096x; 1.1096x over previous
//
#include <hip/hip_runtime.h>
#include <math.h>

// Problem constants: B=2, S=256, IN=80, H=128, NC=40, WSEG=64, F2=256
// Output layout (floats): cls_out[2*256*40]=20480 @0, bin_out[2*256*2]=1024 @20480,
//                         bmask[2*256]=512 @21504, pred_scores[2] @22016

#define OFF_BIN 20480
#define OFF_BM  21504
#define OFF_PRED 22016

__device__ __forceinline__ float preluf(float x, float a) { return x >= 0.f ? x : a * x; }
__device__ __forceinline__ float sigf(float x) { return 1.f / (1.f + __expf(-x)); }
// exact identity tanh(x) = 1 - 2/(e^{2x}+1); hardware v_exp_f32, no branches
__device__ __forceinline__ float tanh_fast(float x) { return 1.f - 2.f / (__expf(2.f * x) + 1.f); }

// ---------------- input projection as tiled GEMM (coalesced):
__global__ __launch_bounds__(256) void k_gemm(const float* __restrict__ A,
                                              const float* __restrict__ B,
                                              int Adim, int K,
                                              const float* __restrict__ wf,
                                              const float* __restrict__ bf,
                                              const float* __restrict__ wb,
                                              const float* __restrict__ bbv,
                                              float* __restrict__ outF,
                                              float* __restrict__ outB) {
    int mtile = blockIdx.y;
    int dir = mtile >> 3;
    const float* W = dir ? wb : wf;
    const float* bias = dir ? bbv : bf;
    float* out = dir ? outB : outF;
    int g0 = (mtile & 7) << 6;
    int tb0 = blockIdx.x << 6;
    int tid = threadIdx.x;
    int Bdim = K - Adim;

    __shared__ float Ws[16][68];
    __shared__ float Xs[16][68];

    int r = tid >> 2, c4 = tid & 3;
    int tbr = tb0 + r;
    int hr = ((tbr & 1) << 8) | (tbr >> 1);
    int ty = tid >> 4;
    int tx = tid & 15;
    float acc[4][4] = {};

    for (int k0 = 0; k0 < K; k0 += 16) {
        float4 wv = *(const float4*)(W + (size_t)(g0 + r) * K + k0 + (c4 << 2));
        const float* src = (k0 < Adim) ? (A + (size_t)hr * Adim + k0)
                                       : (B + (size_t)hr * Bdim + (k0 - Adim));
        float4 xv = *(const float4*)(src + (c4 << 2));
        __syncthreads();
        int kc = c4 << 2;
        Ws[kc + 0][r] = wv.x; Ws[kc + 1][r] = wv.y; Ws[kc + 2][r] = wv.z; Ws[kc + 3][r] = wv.w;
        Xs[kc + 0][r] = xv.x; Xs[kc + 1][r] = xv.y; Xs[kc + 2][r] = xv.z; Xs[kc + 3][r] = xv.w;
        __syncthreads();
#pragma unroll
        for (int kk = 0; kk < 16; ++kk) {
            float4 wq = *(const float4*)&Ws[kk][ty << 2];
            float4 xq = *(const float4*)&Xs[kk][tx << 2];
            acc[0][0] += wq.x * xq.x; acc[0][1] += wq.x * xq.y; acc[0][2] += wq.x * xq.z; acc[0][3] += wq.x * xq.w;
            acc[1][0] += wq.y * xq.x; acc[1][1] += wq.y * xq.y; acc[1][2] += wq.y * xq.z; acc[1][3] += wq.y * xq.w;
            acc[2][0] += wq.z * xq.x; acc[2][1] += wq.z * xq.y; acc[2][2] += wq.z * xq.z; acc[2][3] += wq.z * xq.w;
            acc[3][0] += wq.w * xq.x; acc[3][1] += wq.w * xq.y; acc[3][2] += wq.w * xq.z; acc[3][3] += wq.w * xq.w;
        }
    }
    int gq = g0 + (ty << 2);
    float b0 = bias[gq], b1 = bias[gq + 1], b2 = bias[gq + 2], b3 = bias[gq + 3];
#pragma unroll
    for (int j = 0; j < 4; ++j) {
        int tb = tb0 + (tx << 2) + j;
        float4 v = make_float4(acc[0][j] + b0, acc[1][j] + b1, acc[2][j] + b2, acc[3][j] + b3);
        *(float4*)(out + (size_t)tb * 512 + gq) = v;
    }
}

// ---------------- LSTM scan v5 (R14, kept): 8-step-batched global I/O.
__global__ __launch_bounds__(512, 2) void k_lstm(const float* __restrict__ pre_f,
                                                 const float* __restrict__ pre_b,
                                                 const float* __restrict__ whh_f,
                                                 const float* __restrict__ whh_b,
                                                 float* __restrict__ hout_f,
                                                 float* __restrict__ hout_b) {
    const int dir = blockIdx.x >> 1;
    const int b = blockIdx.x & 1;
    const float* pre = dir ? pre_b : pre_f;
    const float* whh = dir ? whh_b : whh_f;
    float* hout = dir ? hout_b : hout_f;
    const int tid = threadIdx.x;
    const int c = tid >> 7;        // k-chunk 0..3 (wave-uniform)
    const int gg = tid & 127;      // hidden unit 0..127
    const int k0 = c << 5;

    float w[4][32];
#pragma unroll
    for (int j = 0; j < 4; ++j) {
#pragma unroll
        for (int k = 0; k < 32; k += 4) {
            float4 v = *(const float4*)(whh + (size_t)((j << 7) + gg) * 128 + k0 + k);
            w[j][k] = v.x; w[j][k + 1] = v.y; w[j][k + 2] = v.z; w[j][k + 3] = v.w;
        }
    }

    __shared__ __align__(16) float hl[128];
    __shared__ float4 part[4][128];
    if (tid < 128) hl[tid] = 0.f;
    float cst = 0.f;
    float pf0[8], pf1[8], pf2[8], pf3[8], hb8[8];
    __syncthreads();

    for (int blk = 0; blk < 32; ++blk) {
        if (tid < 128) {
#pragma unroll
            for (int s = 0; s < 8; ++s) {
                int step = (blk << 3) + s;
                int t = dir ? (255 - step) : step;
                const float* pp = pre + ((size_t)t * 2 + b) * 512;
                pf0[s] = pp[gg]; pf1[s] = pp[128 + gg];
                pf2[s] = pp[256 + gg]; pf3[s] = pp[384 + gg];
            }
        }
#pragma unroll
        for (int s = 0; s < 8; ++s) {
            float a0 = 0.f, a1 = 0.f, a2 = 0.f, a3 = 0.f;
            float e0 = 0.f, e1 = 0.f, e2 = 0.f, e3 = 0.f;
#pragma unroll
            for (int k = 0; k < 32; k += 8) {
                float4 hA = *(const float4*)(hl + k0 + k);       // wave-uniform broadcast
                float4 hB = *(const float4*)(hl + k0 + k + 4);
                a0 += w[0][k] * hA.x + w[0][k + 1] * hA.y + w[0][k + 2] * hA.z + w[0][k + 3] * hA.w;
                e0 += w[0][k + 4] * hB.x + w[0][k + 5] * hB.y + w[0][k + 6] * hB.z + w[0][k + 7] * hB.w;
                a1 += w[1][k] * hA.x + w[1][k + 1] * hA.y + w[1][k + 2] * hA.z + w[1][k + 3] * hA.w;
                e1 += w[1][k + 4] * hB.x + w[1][k + 5] * hB.y + w[1][k + 6] * hB.z + w[1][k + 7] * hB.w;
                a2 += w[2][k] * hA.x + w[2][k + 1] * hA.y + w[2][k + 2] * hA.z + w[2][k + 3] * hA.w;
                e2 += w[2][k + 4] * hB.x + w[2][k + 5] * hB.y + w[2][k + 6] * hB.z + w[2][k + 7] * hB.w;
                a3 += w[3][k] * hA.x + w[3][k + 1] * hA.y + w[3][k + 2] * hA.z + w[3][k + 3] * hA.w;
                e3 += w[3][k + 4] * hB.x + w[3][k + 5] * hB.y + w[3][k + 6] * hB.z + w[3][k + 7] * hB.w;
            }
            part[c][gg] = make_float4(a0 + e0, a1 + e1, a2 + e2, a3 + e3);
            __syncthreads();
            if (tid < 128) {
                float4 q0 = part[0][gg], q1 = part[1][gg], q2 = part[2][gg], q3 = part[3][gg];
                float gi = pf0[s] + ((q0.x + q1.x) + (q2.x + q3.x));
                float gf = pf1[s] + ((q0.y + q1.y) + (q2.y + q3.y));
                float gG = pf2[s] + ((q0.z + q1.z) + (q2.z + q3.z));
                float go = pf3[s] + ((q0.w + q1.w) + (q2.w + q3.w));
                cst = sigf(gf) * cst + sigf(gi) * tanh_fast(gG);
                float h = sigf(go) * tanh_fast(cst);
                hl[gg] = h;
                hb8[s] = h;
            }
            __syncthreads();
        }
        if (tid < 128) {
            int base = blk << 3;
#pragma unroll
            for (int s = 0; s < 8; ++s) {
                int t = dir ? (255 - (base + s)) : (base + s);
                hout[(size_t)(((b << 8) + t) << 7) + gg] = hb8[s];
            }
        }
    }
}

// ---------------- fused features (unchanged)
__global__ __launch_bounds__(256) void k_feats(const float* __restrict__ h1f,
                                               const float* __restrict__ h1b,
                                               const float* __restrict__ ws1,
                                               const float* __restrict__ bs1,
                                               const float* a_s0,
                                               float* __restrict__ Pd,
                                               float* __restrict__ Pe,
                                               const float* ac0p, const float* __restrict__ wc1,
                                               const float* __restrict__ bc1, const float* ac1p,
                                               const float* __restrict__ wc2, const float* __restrict__ bc2,
                                               const float* ab0p, const float* __restrict__ wb1,
                                               const float* __restrict__ bb1, const float* ab1p,
                                               const float* __restrict__ wb2, const float* __restrict__ bb2,
                                               float* __restrict__ out,
                                               float* __restrict__ cum) {
    __shared__ __align__(16) float xa[256];
    __shared__ __align__(16) float xb2[256];
    __shared__ __align__(16) float hc[80];
    __shared__ __align__(16) float hb[80];
    int bid = blockIdx.x;
    int tid = threadIdx.x;
    int kk = tid & 127;
    if (bid < 512) {
        int row = bid;
        float a0 = a_s0[0];
        float v = ((tid < 128) ? h1f : h1b)[(size_t)row * 128 + kk];
        xa[tid] = preluf(v, a0);
        __syncthreads();
        const float4* p4 = (const float4*)xa;
        if (tid < 100) {
            const float4* wr = (const float4*)(ws1 + (size_t)tid * 768 + 256);
            float acc = bs1[tid];
#pragma unroll 8
            for (int q = 0; q < 64; ++q) {
                float4 w4 = wr[q], x4 = p4[q];
                acc += w4.x * x4.x + w4.y * x4.y + w4.z * x4.z + w4.w * x4.w;
            }
            Pd[(size_t)row * 100 + tid] = acc;
        } else if (tid >= 128 && tid < 228) {
            int u = tid - 128;
            const float4* wr = (const float4*)(ws1 + (size_t)u * 768 + 512);
            float acc = 0.f;
#pragma unroll 8
            for (int q = 0; q < 64; ++q) {
                float4 w4 = wr[q], x4 = p4[q];
                acc += w4.x * x4.x + w4.y * x4.y + w4.z * x4.z + w4.w * x4.w;
            }
            Pe[(size_t)row * 100 + u] = acc;
        }
    } else if (bid < 1024) {
        int row = bid - 512;
        float ac0 = ac0p[0], ac1 = ac1p[0], ab0 = ab0p[0], ab1 = ab1p[0];
        float v = ((tid < 128) ? h1f : h1b)[(size_t)row * 128 + kk];
        xa[tid] = preluf(v, ac0);
        xb2[tid] = preluf(v, ab0);
        __syncthreads();
        if (tid < 80) {
            const float4* wr = (const float4*)(wc1 + (size_t)tid * 256);
            const float4* x4 = (const float4*)xa;
            float acc = bc1[tid];
#pragma unroll 8
            for (int q = 0; q < 64; ++q) {
                float4 w4 = wr[q], p = x4[q];
                acc += w4.x * p.x + w4.y * p.y + w4.z * p.z + w4.w * p.w;
            }
            hc[tid] = preluf(acc, ac1);
        } else if (tid >= 128 && tid < 208) {
            int u = tid - 128;
            const float4* wr = (const float4*)(wb1 + (size_t)u * 256);
            const float4* x4 = (const float4*)xb2;
            float acc = bb1[u];
#pragma unroll 8
            for (int q = 0; q < 64; ++q) {
                float4 w4 = wr[q], p = x4[q];
                acc += w4.x * p.x + w4.y * p.y + w4.z * p.z + w4.w * p.w;
            }
            hb[u] = preluf(acc, ab1);
        }
        __syncthreads();
        if (tid < 40) {
            const float4* wr = (const float4*)(wc2 + (size_t)tid * 80);
            const float4* h4 = (const float4*)hc;
            float acc = bc2[tid];
#pragma unroll
            for (int q = 0; q < 20; ++q) {
                float4 w4 = wr[q], p = h4[q];
                acc += w4.x * p.x + w4.y * p.y + w4.z * p.z + w4.w * p.w;
            }
            out[(size_t)row * 40 + tid] = acc;
        } else if (tid >= 64 && tid < 66) {
            int j = tid - 64;
            const float4* wr = (const float4*)(wb2 + (size_t)j * 80);
            const float4* h4 = (const float4*)hb;
            float acc = bb2[j];
#pragma unroll
            for (int q = 0; q < 20; ++q) {
                float4 w4 = wr[q], p = h4[q];
                acc += w4.x * p.x + w4.y * p.y + w4.z * p.z + w4.w * p.w;
            }
            out[OFF_BIN + (size_t)row * 2 + j] = acc;
        }
    } else {
        int b = bid - 1024;
        const float* src = (tid < 128) ? h1f : h1b;
        float run = 0.f;
#pragma unroll 8
        for (int t = 0; t < 256; ++t) {
            float v = src[(size_t)(((b << 8) + t) << 7) + kk];
            cum[(size_t)(((b << 8) + t) << 8) + tid] = run + v;
            run += v;
        }
    }
}

// ---------------- pairwise scores v4 (exact R13 best-measured): 50 acc/thread,
// 4 blocks/CU. block = (b, e-quad, d-tile 32) -> 1024 blocks.
// lane = (dd = lane&31, eh = lane>>5); thread computes 25 u x 2 e.
__global__ __launch_bounds__(256, 4) void k_scores(const float* __restrict__ cum,
                                                   const float* __restrict__ ws1,
                                                   const float* __restrict__ ws2,
                                                   const float* __restrict__ bs2,
                                                   const float* __restrict__ Pd,
                                                   const float* __restrict__ Pe,
                                                   const float* a_s0p, const float* a_s1p,
                                                   float* __restrict__ scT) {
    int bid = blockIdx.x;
    int dt = bid & 7, et = (bid >> 3) & 63, b = bid >> 9;
    int d0 = dt << 5, e0 = et << 2;
    int tid = threadIdx.x;
    __shared__ float cumd[32][257];   // stride 257: <=2-way bank aliasing (free)
    __shared__ float cume[4][257];
    __shared__ float red[4][4][32];
    float a0 = a_s0p[0], a1 = a_s1p[0];

    // stage cumd: row r = tid&31, 32-float chunk w = tid>>5
    {
        int r = tid & 31, w = tid >> 5;
        const float4* src = (const float4*)(cum + (size_t)(((b << 8) + (d0 + r)) << 8) + (w << 5));
        float* dst = &cumd[r][w << 5];
#pragma unroll
        for (int x = 0; x < 8; ++x) {
            float4 v = src[x];
            dst[(x << 2) + 0] = v.x; dst[(x << 2) + 1] = v.y;
            dst[(x << 2) + 2] = v.z; dst[(x << 2) + 3] = v.w;
        }
    }
    // stage cume: 4 rows x 256
    {
        int er = tid >> 6, j = tid & 63;
        float4 v = *((const float4*)(cum + (size_t)(((b << 8) + (e0 + er)) << 8)) + j);
        float* dst = &cume[er][j << 2];
        dst[0] = v.x; dst[1] = v.y; dst[2] = v.z; dst[3] = v.w;
    }
    __syncthreads();

    int ug = __builtin_amdgcn_readfirstlane(tid >> 6);  // wave-uniform u-group 0..3
    int lane = tid & 63;
    int dd = lane & 31;           // d within 32-tile
    int eh = lane >> 5;           // e-half 0/1
    int ea = (eh << 1), ebn = ea + 1;   // this thread's two e-locals
    float acc0[25], acc1[25];
#pragma unroll
    for (int t = 0; t < 25; ++t) { acc0[t] = 0.f; acc1[t] = 0.f; }
    const float* wc = ws1 + (size_t)(ug * 25) * 768;  // c-block columns are [0,256)

    for (int k = 0; k < 256; k += 4) {
        float cd0 = cumd[dd][k], cd1 = cumd[dd][k + 1], cd2 = cumd[dd][k + 2], cd3 = cumd[dd][k + 3];
        float4 ya = make_float4(preluf(cume[ea][k] - cd0, a0), preluf(cume[ea][k + 1] - cd1, a0),
                                preluf(cume[ea][k + 2] - cd2, a0), preluf(cume[ea][k + 3] - cd3, a0));
        float4 yb = make_float4(preluf(cume[ebn][k] - cd0, a0), preluf(cume[ebn][k + 1] - cd1, a0),
                                preluf(cume[ebn][k + 2] - cd2, a0), preluf(cume[ebn][k + 3] - cd3, a0));
#pragma unroll
        for (int t = 0; t < 25; ++t) {
            float4 wq = *(const float4*)(wc + (size_t)t * 768 + k);  // uniform -> s_load_dwordx4
            acc0[t] += ya.x * wq.x + ya.y * wq.y + ya.z * wq.z + ya.w * wq.w;
            acc1[t] += yb.x * wq.x + yb.y * wq.y + yb.z * wq.z + yb.w * wq.w;
        }
    }

    const float* pdrow = Pd + (size_t)((b << 8) + d0 + dd) * 100;
    {
        const float* perow = Pe + (size_t)((b << 8) + e0 + ea) * 100;
        float part = 0.f;
#pragma unroll
        for (int t = 0; t < 25; ++t) {
            int u = ug * 25 + t;
            float h = acc0[t] + pdrow[u] + perow[u];
            part += preluf(h, a1) * ws2[u];
        }
        red[ug][ea][dd] = part;
    }
    {
        const float* perow = Pe + (size_t)((b << 8) + e0 + ebn) * 100;
        float part = 0.f;
#pragma unroll
        for (int t = 0; t < 25; ++t) {
            int u = ug * 25 + t;
            float h = acc1[t] + pdrow[u] + perow[u];
            part += preluf(h, a1) * ws2[u];
        }
        red[ug][ebn][dd] = part;
    }
    __syncthreads();
    if (tid < 128) {
        int e = tid >> 5, l2 = tid & 31;
        float s = red[0][e][l2] + red[1][e][l2] + red[2][e][l2] + red[3][e][l2] + bs2[0];
        scT[(size_t)(((b << 8) + (e0 + e)) << 8) + d0 + l2] = s;
    }
}

// ---------------- banded DP + backtrack (R11 version, unchanged)
__device__ __forceinline__ void argmax_dpp(float& v, int& ki) {
#define AD_STEP(CTRL, RMASK)                                                                    \
    {                                                                                           \
        int mv = __builtin_amdgcn_update_dpp(__float_as_int(v), __float_as_int(v), CTRL, RMASK, 0xf, false); \
        int mk = __builtin_amdgcn_update_dpp(ki, ki, CTRL, RMASK, 0xf, false);                  \
        float fv = __int_as_float(mv);                                                          \
        bool take = (fv > v) || (fv == v && mk < ki);                                           \
        v = take ? fv : v;                                                                      \
        ki = take ? mk : ki;                                                                    \
    }
    AD_STEP(0x111, 0xf)   // row_shr:1
    AD_STEP(0x112, 0xf)   // row_shr:2
    AD_STEP(0x114, 0xf)   // row_shr:4
    AD_STEP(0x118, 0xf)   // row_shr:8
    AD_STEP(0x142, 0xa)   // row_bcast15
    AD_STEP(0x143, 0xc)   // row_bcast31 -> lane 63 = global
#undef AD_STEP
}

__global__ __launch_bounds__(128) void k_dp(const float* __restrict__ scT,
                                            const int* __restrict__ lengths,
                                            float* __restrict__ out) {
    __shared__ int bp[2][256];
    __shared__ float bm[2][256];
    int tid = threadIdx.x;
    for (int i = tid; i < 512; i += 128) {
        ((int*)bp)[i] = 0;
        ((float*)bm)[i] = 0.f;
    }
    __syncthreads();
    int b = tid >> 6, ln = tid & 63;
    const float* sb = scT + ((size_t)b << 16);
    int lenm1 = lengths[b] - 1;
    float wreg = 0.f;
    float bestFinal = 0.f;
    int jcur = (ln < 1) ? ln : ln - 64;
    float sc_next = sb[(1 << 8) + ((jcur < 0) ? 0 : jcur)];
    for (int i = 1; i < 256; ++i) {
        float sc = sc_next;
        int j = jcur;
        if (i < 255) {
            int m2 = (i + 1) & 63;
            int base2 = (i + 1) - m2;
            int j2 = (ln < m2) ? (base2 + ln) : (base2 + ln - 64);
            jcur = j2;
            sc_next = sb[((i + 1) << 8) + ((j2 < 0) ? 0 : j2)];
        }
        float v = (j >= 0) ? (wreg + sc) : -1000000000.0f;
        int ki = j;
        argmax_dpp(v, ki);
        float bv = __uint_as_float(__builtin_amdgcn_readlane(__float_as_uint(v), 63));
        int bk = __builtin_amdgcn_readlane(ki, 63);
        if (ln == (i & 63)) wreg = bv;
        if (ln == 0) bp[b][i] = bk;
        if (i == lenm1) bestFinal = bv;
    }
    if (ln == 0) out[OFF_PRED + b] = bestFinal;
    __syncthreads();
    if (tid < 2) {
        int bb = tid;
        int cur = lengths[bb] - 1;
        for (int it = 0; it < 256; ++it) {
            bm[bb][cur] = 1.f;
            int prev = bp[bb][cur];
            cur = (cur > 0) ? prev : 0;
        }
    }
    __syncthreads();
    for (int i = tid; i < 512; i += 128) out[OFF_BM + i] = ((float*)bm)[i];
}

extern "C" void kernel_launch(void* const* d_in, const int* in_sizes, int n_in,
                              void* d_out, int out_size, void* d_ws, size_t ws_size,
                              hipStream_t stream) {
    const float* x     = (const float*)d_in[0];
    const int* lengths = (const int*)d_in[1];
    const float* wih0f = (const float*)d_in[2];
    const float* whh0f = (const float*)d_in[3];
    const float* b0f   = (const float*)d_in[4];
    const float* wih0b = (const float*)d_in[5];
    const float* whh0b = (const float*)d_in[6];
    const float* b0b   = (const float*)d_in[7];
    const float* wih1f = (const float*)d_in[8];
    const float* whh1f = (const float*)d_in[9];
    const float* b1f   = (const float*)d_in[10];
    const float* wih1b = (const float*)d_in[11];
    const float* whh1b = (const float*)d_in[12];
    const float* b1b   = (const float*)d_in[13];
    const float* a_s0  = (const float*)d_in[14];
    const float* w_s1  = (const float*)d_in[15];
    const float* b_s1  = (const float*)d_in[16];
    const float* a_s1  = (const float*)d_in[17];
    const float* w_s2  = (const float*)d_in[18];
    const float* b_s2  = (const float*)d_in[19];
    const float* a_c0  = (const float*)d_in[20];
    const float* w_c1  = (const float*)d_in[21];
    const float* b_c1  = (const float*)d_in[22];
    const float* a_c1  = (const float*)d_in[23];
    const float* w_c2  = (const float*)d_in[24];
    const float* b_c2  = (const float*)d_in[25];
    const float* a_b0  = (const float*)d_in[26];
    const float* w_b1  = (const float*)d_in[27];
    const float* b_b1  = (const float*)d_in[28];
    const float* a_b1  = (const float*)d_in[29];
    const float* w_b2  = (const float*)d_in[30];
    const float* b_b2  = (const float*)d_in[31];

    float* wsf = (float*)d_ws;
    float* preF = wsf;                 // 262144
    float* preB = wsf + 262144;        // 262144
    float* h0f  = wsf + 524288;        // 65536
    float* h0b  = wsf + 589824;        // 65536
    float* h1f  = wsf + 655360;        // 65536
    float* h1b  = wsf + 720896;        // 65536
    float* cum  = wsf + 786432;        // 131072
    float* Pd   = wsf + 917504;        // 51200
    float* Pe   = wsf + 968704;        // 51200
    float* scT  = wsf + 1019904;       // 131072
    float* out  = (float*)d_out;

    // layer 0 (tiled GEMM input projection, both dirs)
    k_gemm<<<dim3(8, 16), 256, 0, stream>>>(x, x, 80, 80, wih0f, b0f, wih0b, b0b, preF, preB);
    k_lstm<<<4, 512, 0, stream>>>(preF, preB, whh0f, whh0b, h0f, h0b);
    // layer 1
    k_gemm<<<dim3(8, 16), 256, 0, stream>>>(h0f, h0b, 128, 256, wih1f, b1f, wih1b, b1b, preF, preB);
    k_lstm<<<4, 512, 0, stream>>>(preF, preB, whh1f, whh1b, h1f, h1b);
    // fused features: Pd/Pe + heads + cumsum
    k_feats<<<1026, 256, 0, stream>>>(h1f, h1b, w_s1, b_s1, a_s0, Pd, Pe,
                                      a_c0, w_c1, b_c1, a_c1, w_c2, b_c2,
                                      a_b0, w_b1, b_b1, a_b1, w_b2, b_b2, out, cum);
    // pairwise scores (v4: 32-d tile, 50 acc, 4 blocks/CU)
    k_scores<<<1024, 256, 0, stream>>>(cum, w_s1, w_s2, b_s2, Pd, Pe, a_s0, a_s1, scT);
    // DP + backtrack (DPP argmax + register window)
    k_dp<<<1, 128, 0, stream>>>(scT, lengths, out);
}